// Round 2
// baseline (836.806 us; speedup 1.0000x reference)
//
#include <hip/hip_runtime.h>
#include <hip/hip_bf16.h>
#include <cstdint>
#include <cstddef>

// Problem: B=16, N=128, D=S=128, hidden=256. fp32 I/O, bf16 MFMA internals.
// Pipeline (4 launches):
//   proj_kernel : Pa/Qab/Pm/Qmb node projections (folds b1a/b1m) -> ws fp32;
//                 mat-0 blocks also zero the agg buffer (for atomicAdd).
//   wswz_kernel : fp32->bf16 PLAIN transpose of W1a[256:384], W2a,
//                 W1m[256:384], W2m -> ws (B-operand frags read from global).
//   fused_mlp   : 64-row tile per block (grid 4096 = 16b x 128p x 2 halves):
//                   edge MLP (B-frags direct from global, H1 via 2x8KB LDS
//                   dbuf, 1 barrier/h) -> relu*mask=e -> BN'd edges to d_out,
//                   e(bf16) redistributed through the H1 buffers -> msg MLP
//                   -> relu*mask -> 64-row column-sum -> atomicAdd into agg.
//                 No GLDS weight staging => no vmcnt(0)-drain serialization.
//   update      : VALU update-MLP(concat(nodes,agg)) + node BN -> d_out nodes
// LDS ~20KB, est. VGPR ~120 -> 3-4 blocks/CU (12-16 waves) for latency hiding.

typedef __attribute__((ext_vector_type(8))) __bf16 bf16x8;
typedef __attribute__((ext_vector_type(4))) __bf16 bf16x4;
typedef __attribute__((ext_vector_type(4))) float f32x4;

__device__ inline bf16x8 load8_cvt(const float* __restrict__ p) {
  const float4 a = *(const float4*)p;
  const float4 b = *(const float4*)(p + 4);
  bf16x8 r;
  r[0] = (__bf16)a.x; r[1] = (__bf16)a.y; r[2] = (__bf16)a.z; r[3] = (__bf16)a.w;
  r[4] = (__bf16)b.x; r[5] = (__bf16)b.y; r[6] = (__bf16)b.z; r[7] = (__bf16)b.w;
  return r;
}

// ---------------- prep: node projections (fp32) + agg zeroing ----------------
// mat 0: Pa  = nodes @ W1a[0:128]        (state_i side, varies per row q)
// mat 1: Qab = nodes @ W1a[128:256]+b1a  (state_j side, block-constant p)
// mat 2: Pm  = nodes @ W1m[0:128]
// mat 3: Qmb = nodes @ W1m[128:256]+b1m
__global__ void __launch_bounds__(256) proj_kernel(
    const float* __restrict__ nodes, const float* __restrict__ W1a,
    const float* __restrict__ b1a, const float* __restrict__ W1m,
    const float* __restrict__ b1m, float* __restrict__ outP,
    float* __restrict__ agg) {
  __shared__ float x[8][128];
  const int mat = blockIdx.y;
  const int t = threadIdx.x;
  if (mat == 0) {  // zero agg (2048*128 floats) for fused kernel's atomicAdd
#pragma unroll
    for (int i = 0; i < 4; ++i) agg[blockIdx.x * 1024 + i * 256 + t] = 0.f;
  }
  const float* W = (mat < 2 ? W1a : W1m) + ((mat & 1) ? 128 * 256 : 0);
  float* out = outP + (size_t)mat * (2048 * 256);
  const int r0 = blockIdx.x * 8;
  for (int i = t; i < 1024; i += 256)
    x[i >> 7][i & 127] = nodes[r0 * 128 + i];
  __syncthreads();
  float bv = 0.f;
  if (mat == 1) bv = b1a[t];
  if (mat == 3) bv = b1m[t];
  float acc[8];
#pragma unroll
  for (int r = 0; r < 8; ++r) acc[r] = bv;
  for (int k = 0; k < 128; ++k) {
    float w = W[k * 256 + t];
#pragma unroll
    for (int r = 0; r < 8; ++r) acc[r] += x[r][k] * w;
  }
  for (int r = 0; r < 8; ++r) out[(size_t)(r0 + r) * 256 + t] = acc[r];
}

// ---------------- prep: weight fp32->bf16 plain transpose ----------------
// W1-type (K=128 rows, N=256 cols): src[k*256+n] -> d[n*128+k]
// W2-type (K=256 rows, N=128 cols): src[k*128+n] -> d[n*256+k]
__global__ void __launch_bounds__(256) wswz_kernel(
    const float* __restrict__ W1a, const float* __restrict__ W2a,
    const float* __restrict__ W1m, const float* __restrict__ W2m,
    __hip_bfloat16* __restrict__ dstp) {
  __bf16* dst = (__bf16*)dstp;
  const int mat = blockIdx.y;
  const float* src;
  __bf16* d;
  if (mat == 0)      { src = W1a + 65536; d = dst; }
  else if (mat == 1) { src = W2a;         d = dst + 32768; }
  else if (mat == 2) { src = W1m + 65536; d = dst + 65536; }
  else               { src = W2m;         d = dst + 98304; }
  const int base = (blockIdx.x * 256 + threadIdx.x) * 4;
  bf16x4 v;
  if (mat == 0 || mat == 2) {
    const int n = base >> 7, k0 = base & 127;
#pragma unroll
    for (int i = 0; i < 4; ++i) v[i] = (__bf16)src[(k0 + i) * 256 + n];
    *(bf16x4*)(d + n * 128 + k0) = v;
  } else {
    const int n = base >> 8, k0 = base & 255;
#pragma unroll
    for (int i = 0; i < 4; ++i) v[i] = (__bf16)src[(k0 + i) * 128 + n];
    *(bf16x4*)(d + n * 256 + k0) = v;
  }
}

// ---------------- fused edge-MLP -> msg-MLP -> agg ----------------
__global__ void __launch_bounds__(256, 2) fused_mlp_kernel(
    const float* __restrict__ edges, const float* __restrict__ mask,
    const float* __restrict__ b2a, const float* __restrict__ b2m,
    const float* __restrict__ ge, const float* __restrict__ be,
    const float* __restrict__ me, const float* __restrict__ ve,
    const float* __restrict__ Pa, const float* __restrict__ Qab,
    const float* __restrict__ Pm, const float* __restrict__ Qmb,
    const __hip_bfloat16* __restrict__ Wsw, float* __restrict__ edges_out,
    float* __restrict__ agg) {
  __shared__ __align__(16) char sH[2][8192];  // H1 dbuf / X2 halves / sAgg
  __shared__ float sQ[256];
  __shared__ float sB2a[128], sB2m[128], sScE[128], sShE[128];
  __shared__ float sMask[64];

  const int t = threadIdx.x;
  const int lane = t & 63, wv = t >> 6;
  const int cl = lane & 15, qd = lane >> 4;
  const int m0 = wv << 4;  // 16 rows per wave

  const int bb = blockIdx.x >> 8;        // 16 batches
  const int p = (blockIdx.x >> 1) & 127; // 128 p-tiles
  const int q0 = (blockIdx.x & 1) << 6;  // 2 half-tiles of 64 q-rows

  if (t < 128) {
    sB2a[t] = b2a[t];
    sB2m[t] = b2m[t];
    float sc = ge[t] * rsqrtf(ve[t] + 1e-3f);
    sScE[t] = sc;
    sShE[t] = be[t] - me[t] * sc;
  }
  if (t < 64) sMask[t] = mask[(bb << 14) + (p << 7) + q0 + t];
  sQ[t] = Qab[((bb << 7) + p) * 256 + t];
  __syncthreads();

  // ----- edge X fragments (fp32 -> bf16), rows q0+m0..q0+m0+15 -----
  const float* Xb = edges + ((size_t)((bb << 14) + (p << 7) + q0) << 7);
  bf16x8 xf[4];
#pragma unroll
  for (int ks = 0; ks < 4; ++ks)
    xf[ks] = load8_cvt(Xb + (m0 + cl) * 128 + ks * 32 + qd * 8);

  f32x4 ne[8];
#pragma unroll
  for (int nt = 0; nt < 8; ++nt) {
    float bv = sB2a[nt * 16 + cl];
    ne[nt] = (f32x4){bv, bv, bv, bv};
  }

  const __bf16* w1 = (const __bf16*)Wsw;           // W1ae^T [256][128]
  const __bf16* w2 = (const __bf16*)Wsw + 32768;   // W2a^T  [128][256]
  const float* Prow = Pa + (size_t)((bb << 7) + q0 + m0 + qd * 4) * 256;

  // ===== phase 1: edge MLP (1 barrier per h via H dbuf) =====
#pragma unroll 1
  for (int h = 0; h < 4; ++h) {
    f32x4 a1[4];
#pragma unroll
    for (int nt = 0; nt < 4; ++nt) {
      const int col = h * 64 + nt * 16 + cl;
      const float qv = sQ[col];
      a1[nt] = (f32x4){Prow[col] + qv, Prow[256 + col] + qv,
                       Prow[512 + col] + qv, Prow[768 + col] + qv};
    }
#pragma unroll
    for (int ks = 0; ks < 4; ++ks)
#pragma unroll
      for (int nt = 0; nt < 4; ++nt) {
        bf16x8 bw = *(const bf16x8*)(w1 + (h * 64 + nt * 16 + cl) * 128 +
                                     ks * 32 + qd * 8);
        a1[nt] = __builtin_amdgcn_mfma_f32_16x16x32_bf16(xf[ks], bw, a1[nt], 0, 0, 0);
      }
    char* const Hb = sH[h & 1];
#pragma unroll
    for (int nt = 0; nt < 4; ++nt) {
      const int kq = nt * 16 + cl;
#pragma unroll
      for (int r = 0; r < 4; ++r) {
        const int m = m0 + qd * 4 + r;
        float v = a1[nt][r];
        v = v > 0.f ? v : 0.f;
        *(__bf16*)(Hb + m * 128 + ((((kq >> 3) ^ m) & 7) << 4) + ((kq & 7) << 1)) =
            (__bf16)v;
      }
    }
    __syncthreads();  // H(h) visible (dbuf: only sync in the loop)
    bf16x8 hf[2];
#pragma unroll
    for (int ks = 0; ks < 2; ++ks) {
      const int m = m0 + cl;
      const int gs = ((ks * 4 + qd) ^ m) & 7;
      hf[ks] = *(const bf16x8*)(Hb + m * 128 + gs * 16);
    }
#pragma unroll
    for (int ks = 0; ks < 2; ++ks)
#pragma unroll
      for (int nt = 0; nt < 8; ++nt) {
        bf16x8 bw = *(const bf16x8*)(w2 + (nt * 16 + cl) * 256 + h * 64 +
                                     ks * 32 + qd * 8);
        ne[nt] = __builtin_amdgcn_mfma_f32_16x16x32_bf16(hf[ks], bw, ne[nt], 0, 0, 0);
      }
  }

  // ===== epilogue 1: relu*mask -> BN'd fp32 edges out + bf16 X2 into sH =====
  __syncthreads();  // phase-1 readers of sH / sQ done
  sQ[t] = Qmb[((bb << 7) + p) * 256 + t];
  {
    float* Ob = edges_out + ((size_t)((bb << 14) + (p << 7) + q0) << 7);
#pragma unroll
    for (int nt = 0; nt < 8; ++nt) {
      const int col = nt * 16 + cl;
      const float sc = sScE[col], sh = sShE[col];
      char* const buf = sH[(nt >> 2) & 1];
      const int kq = col & 63;
#pragma unroll
      for (int r = 0; r < 4; ++r) {
        const int m = m0 + qd * 4 + r;
        float v = ne[nt][r];
        v = v > 0.f ? v : 0.f;
        const float e = v * sMask[m];
        Ob[m * 128 + col] = e * sc + sh;
        *(__bf16*)(buf + m * 128 + ((((kq >> 3) ^ m) & 7) << 4) + ((kq & 7) << 1)) =
            (__bf16)e;
      }
    }
  }
  __syncthreads();  // X2 + sQ(=Qmb) visible

  bf16x8 xf2[4];
#pragma unroll
  for (int ks = 0; ks < 4; ++ks) {
    const int m = m0 + cl;
    const int gs = (((ks & 1) * 4 + qd) ^ m) & 7;
    xf2[ks] = *(const bf16x8*)(sH[(ks >> 1) & 1] + m * 128 + gs * 16);
  }
  __syncthreads();  // X2 reads done before phase-2 overwrites sH

  f32x4 ms[8];
#pragma unroll
  for (int nt = 0; nt < 8; ++nt) {
    float bv = sB2m[nt * 16 + cl];
    ms[nt] = (f32x4){bv, bv, bv, bv};
  }

  const __bf16* w1m = (const __bf16*)Wsw + 65536;  // W1me^T [256][128]
  const __bf16* w2m = (const __bf16*)Wsw + 98304;  // W2m^T  [128][256]
  const float* Pmrow = Pm + (size_t)((bb << 7) + q0 + m0 + qd * 4) * 256;

  // ===== phase 2: message MLP =====
#pragma unroll 1
  for (int h = 0; h < 4; ++h) {
    f32x4 a1[4];
#pragma unroll
    for (int nt = 0; nt < 4; ++nt) {
      const int col = h * 64 + nt * 16 + cl;
      const float qv = sQ[col];
      a1[nt] = (f32x4){Pmrow[col] + qv, Pmrow[256 + col] + qv,
                       Pmrow[512 + col] + qv, Pmrow[768 + col] + qv};
    }
#pragma unroll
    for (int ks = 0; ks < 4; ++ks)
#pragma unroll
      for (int nt = 0; nt < 4; ++nt) {
        bf16x8 bw = *(const bf16x8*)(w1m + (h * 64 + nt * 16 + cl) * 128 +
                                     ks * 32 + qd * 8);
        a1[nt] = __builtin_amdgcn_mfma_f32_16x16x32_bf16(xf2[ks], bw, a1[nt], 0, 0, 0);
      }
    char* const Hb = sH[h & 1];
#pragma unroll
    for (int nt = 0; nt < 4; ++nt) {
      const int kq = nt * 16 + cl;
#pragma unroll
      for (int r = 0; r < 4; ++r) {
        const int m = m0 + qd * 4 + r;
        float v = a1[nt][r];
        v = v > 0.f ? v : 0.f;
        *(__bf16*)(Hb + m * 128 + ((((kq >> 3) ^ m) & 7) << 4) + ((kq & 7) << 1)) =
            (__bf16)v;
      }
    }
    __syncthreads();
    bf16x8 hf[2];
#pragma unroll
    for (int ks = 0; ks < 2; ++ks) {
      const int m = m0 + cl;
      const int gs = ((ks * 4 + qd) ^ m) & 7;
      hf[ks] = *(const bf16x8*)(Hb + m * 128 + gs * 16);
    }
#pragma unroll
    for (int ks = 0; ks < 2; ++ks)
#pragma unroll
      for (int nt = 0; nt < 8; ++nt) {
        bf16x8 bw = *(const bf16x8*)(w2m + (nt * 16 + cl) * 256 + h * 64 +
                                     ks * 32 + qd * 8);
        ms[nt] = __builtin_amdgcn_mfma_f32_16x16x32_bf16(hf[ks], bw, ms[nt], 0, 0, 0);
      }
  }

  // ===== epilogue 2: relu*mask, 64-row column-sum, atomic into agg =====
  float ss[8];
#pragma unroll
  for (int nt = 0; nt < 8; ++nt) {
    float s = 0.f;
#pragma unroll
    for (int r = 0; r < 4; ++r) {
      const int m = m0 + qd * 4 + r;
      float v = ms[nt][r];
      v = v > 0.f ? v : 0.f;
      s += v * sMask[m];
    }
    s += __shfl_xor(s, 16);
    s += __shfl_xor(s, 32);
    ss[nt] = s;
  }
  __syncthreads();  // all sH readers done before sAgg overlay writes
  float* const sAgg = (float*)sH[0];
  if (lane < 16) {
#pragma unroll
    for (int nt = 0; nt < 8; ++nt) sAgg[wv * 128 + nt * 16 + lane] = ss[nt];
  }
  __syncthreads();
  if (t < 128)
    atomicAdd(&agg[((bb << 7) + p) * 128 + t],
              sAgg[t] + sAgg[128 + t] + sAgg[256 + t] + sAgg[384 + t]);
}

// ---------------- kernel C: update MLP + node BN (VALU, tiny) ----------------
__global__ void __launch_bounds__(256) update_kernel(
    const float* __restrict__ nodes, const float* __restrict__ agg,
    const float* __restrict__ W1u, const float* __restrict__ b1u,
    const float* __restrict__ W2u, const float* __restrict__ b2u,
    const float* __restrict__ gn, const float* __restrict__ btn,
    const float* __restrict__ mn, const float* __restrict__ vn,
    float* __restrict__ out) {
  __shared__ float x[8][256];
  __shared__ float hh[8][256];
  const int t = threadIdx.x;
  const int r0 = blockIdx.x * 8;
  for (int i = t; i < 2048; i += 256) {
    int r = i >> 8, c = i & 255;
    x[r][c] = (c < 128) ? nodes[(r0 + r) * 128 + c] : agg[(r0 + r) * 128 + (c - 128)];
  }
  __syncthreads();
  float acc[8];
  {
    float bv = b1u[t];
#pragma unroll
    for (int r = 0; r < 8; ++r) acc[r] = bv;
  }
  for (int k = 0; k < 256; ++k) {
    float w = W1u[k * 256 + t];
#pragma unroll
    for (int r = 0; r < 8; ++r) acc[r] += x[r][k] * w;
  }
#pragma unroll
  for (int r = 0; r < 8; ++r) hh[r][t] = acc[r] > 0.f ? acc[r] : 0.f;
  __syncthreads();
  const int j = t & 127, half = t >> 7;
  float a2[4];
  {
    float bv = b2u[j];
#pragma unroll
    for (int r = 0; r < 4; ++r) a2[r] = bv;
  }
  for (int k = 0; k < 256; ++k) {
    float w = W2u[k * 128 + j];
#pragma unroll
    for (int r = 0; r < 4; ++r) a2[r] += hh[half * 4 + r][k] * w;
  }
  float sc = gn[j] * rsqrtf(vn[j] + 1e-3f);
  float sh = btn[j] - mn[j] * sc;
#pragma unroll
  for (int r = 0; r < 4; ++r) {
    float v = a2[r] > 0.f ? a2[r] : 0.f;
    out[(r0 + half * 4 + r) * 128 + j] = v * sc + sh;
  }
}

extern "C" void kernel_launch(void* const* d_in, const int* in_sizes, int n_in,
                              void* d_out, int out_size, void* d_ws,
                              size_t ws_size, hipStream_t stream) {
  (void)in_sizes; (void)n_in; (void)out_size; (void)ws_size;
  const float* nodes = (const float*)d_in[0];
  const float* edges = (const float*)d_in[1];
  const float* mask = (const float*)d_in[2];
  const float* W1a = (const float*)d_in[3];
  const float* b1a = (const float*)d_in[4];
  const float* W2a = (const float*)d_in[5];
  const float* b2a = (const float*)d_in[6];
  const float* W1m = (const float*)d_in[7];
  const float* b1m = (const float*)d_in[8];
  const float* W2m = (const float*)d_in[9];
  const float* b2m = (const float*)d_in[10];
  const float* W1u = (const float*)d_in[11];
  const float* b1u = (const float*)d_in[12];
  const float* W2u = (const float*)d_in[13];
  const float* b2u = (const float*)d_in[14];
  const float* gn = (const float*)d_in[15];
  const float* btn = (const float*)d_in[16];
  const float* mn = (const float*)d_in[17];
  const float* vn = (const float*)d_in[18];
  const float* ge = (const float*)d_in[19];
  const float* be = (const float*)d_in[20];
  const float* me = (const float*)d_in[21];
  const float* ve = (const float*)d_in[22];

  float* out_nodes = (float*)d_out;
  float* out_edges = (float*)d_out + 262144;

  char* ws = (char*)d_ws;
  float* Pa = (float*)(ws);
  float* Qab = (float*)(ws + ((size_t)1 << 21));
  float* Pm = (float*)(ws + ((size_t)2 << 21));
  float* Qmb = (float*)(ws + ((size_t)3 << 21));
  float* agg = (float*)(ws + ((size_t)4 << 21));
  __hip_bfloat16* Wsw = (__hip_bfloat16*)(ws + ((size_t)4 << 21) + ((size_t)1 << 20));

  proj_kernel<<<dim3(256, 4), 256, 0, stream>>>(nodes, W1a, b1a, W1m, b1m, Pa, agg);
  wswz_kernel<<<dim3(32, 4), 256, 0, stream>>>(W1a, W2a, W1m, W2m, Wsw);
  fused_mlp_kernel<<<4096, 256, 0, stream>>>(edges, mask, b2a, b2m, ge, be, me,
                                             ve, Pa, Qab, Pm, Qmb, Wsw,
                                             out_edges, agg);
  update_kernel<<<256, 256, 0, stream>>>(nodes, agg, W1u, b1u, W2u, b2u, gn, btn,
                                         mn, vn, out_nodes);
}

// Round 3
// 524.413 us; speedup vs baseline: 1.5957x; 1.5957x over previous
//
#include <hip/hip_runtime.h>
#include <hip/hip_bf16.h>
#include <cstdint>
#include <cstddef>

// B=16, N=128, D=S=128, hidden=256. fp32 I/O, bf16 MFMA internals.
// Pipeline (5 launches):
//   proj_kernel : node projections -> ws. Pa/Pm stored TRANSPOSED
//                 ([bb][col][q], float4-loadable per MFMA C-frag); Qab row-
//                 major (+b1a); Qmb row-major (+b1m + cc un-BN constant).
//                 mat-0 blocks zero agg.
//   wswz_kernel : fp32->bf16 transpose+XOR-swizzle of W1a[256:384], W2a,
//                 W1m[256:384] (rows scaled 1/sc_e = un-BN fold), W2m.
//   edge_mlp    : grid 256 x 512thr. Stage 128KB swizzled weights into LDS
//                 ONCE, then 8 tiles/block with ZERO barriers: per-wave 16-row
//                 stripes, per-wave-private H1 LDS slice (same-wave DS order,
//                 no __syncthreads), register-double-buffered X prefetch.
//                 Output: BN'd fp32 edges (final).
//   msg_mlp     : same skeleton; reads BN'd edges (un-BN folded into weights/
//                 Qmb), message MLP, relu*mask, column-sum, atomicAdd agg.
//   update      : VALU update-MLP + node BN -> out nodes.
// LDS 147456B -> 1 block/CU, 8 waves; barrier-free main loop supplies the
// latency hiding that occupancy can't.

typedef __attribute__((ext_vector_type(8))) __bf16 bf16x8;
typedef __attribute__((ext_vector_type(4))) float f32x4;

#define GLDS(gp, lp)                                                        \
  __builtin_amdgcn_global_load_lds(                                         \
      (const __attribute__((address_space(1))) void*)(gp),                  \
      (__attribute__((address_space(3))) void*)(lp), 16, 0, 0)

__device__ inline bf16x8 load8_cvt(const float* __restrict__ p) {
  const float4 a = *(const float4*)p;
  const float4 b = *(const float4*)(p + 4);
  bf16x8 r;
  r[0] = (__bf16)a.x; r[1] = (__bf16)a.y; r[2] = (__bf16)a.z; r[3] = (__bf16)a.w;
  r[4] = (__bf16)b.x; r[5] = (__bf16)b.y; r[6] = (__bf16)b.z; r[7] = (__bf16)b.w;
  return r;
}

// ---------------- prep: node projections ----------------
// mat 0: PaT[bb][col][q] = (nodes @ W1a[0:128])^T        (state_i, per-q)
// mat 1: Qab[bb*128+p][col] = nodes @ W1a[128:256]+b1a   (state_j, per-p)
// mat 2: PmT[bb][col][q] = (nodes @ W1m[0:128])^T
// mat 3: Qmb[bb*128+p][col] = nodes @ W1m[128:256]+b1m+cc,
//        cc = -(sh_e/sc_e) @ W1m[256:384]  (un-BN fold)
__global__ void __launch_bounds__(256) proj_kernel(
    const float* __restrict__ nodes, const float* __restrict__ W1a,
    const float* __restrict__ b1a, const float* __restrict__ W1m,
    const float* __restrict__ b1m, const float* __restrict__ ge,
    const float* __restrict__ be, const float* __restrict__ me,
    const float* __restrict__ ve, float* __restrict__ outP,
    float* __restrict__ agg) {
  __shared__ float x[8][128];
  const int mat = blockIdx.y;
  const int t = threadIdx.x;
  if (mat == 0) {  // zero agg (2048*128 floats) for msg kernel's atomicAdd
#pragma unroll
    for (int i = 0; i < 4; ++i) agg[blockIdx.x * 1024 + i * 256 + t] = 0.f;
  }
  const float* W = (mat < 2 ? W1a : W1m) + ((mat & 1) ? 128 * 256 : 0);
  float* out = outP + (size_t)mat * (2048 * 256);
  const int r0 = blockIdx.x * 8;
  for (int i = t; i < 1024; i += 256)
    x[i >> 7][i & 127] = nodes[r0 * 128 + i];
  __syncthreads();
  float bv = 0.f;
  if (mat == 1) bv = b1a[t];
  if (mat == 3) {
    bv = b1m[t];
    const float* We = W1m + 65536;  // rows 256..383 (edge part)
    float cc = 0.f;
    for (int k = 0; k < 128; ++k) {
      float sc = ge[k] * rsqrtf(ve[k] + 1e-3f);
      float sh = be[k] - me[k] * sc;
      cc -= (sh / sc) * We[k * 256 + t];
    }
    bv += cc;
  }
  float acc[8];
#pragma unroll
  for (int r = 0; r < 8; ++r) acc[r] = bv;
  for (int k = 0; k < 128; ++k) {
    float w = W[k * 256 + t];
#pragma unroll
    for (int r = 0; r < 8; ++r) acc[r] += x[r][k] * w;
  }
  if (mat == 0 || mat == 2) {  // transposed write: [bb][col=t][q0..q0+7]
    const int bb = r0 >> 7, q0 = r0 & 127;
    float* o = out + ((size_t)((bb << 8) + t) << 7) + q0;
#pragma unroll
    for (int r = 0; r < 8; ++r) o[r] = acc[r];
  } else {
    for (int r = 0; r < 8; ++r) out[(size_t)(r0 + r) * 256 + t] = acc[r];
  }
}

// ---------------- prep: weight fp32->bf16 transpose + XOR swizzle ------------
// W1-type (K=128, N=256): dst[n*128 + gs*8 + (k&7)], g=k>>3, gs=(g&8)|((g^n)&7)
// W2-type (K=256, N=128): dst[(k>>6)*8192 + n*64 + (((k>>3)^n)&7)*8 + (k&7)]
// mat2 (W1me) rows scaled by 1/sc_e[k] (un-BN fold).
__global__ void __launch_bounds__(256) wswz_kernel(
    const float* __restrict__ W1a, const float* __restrict__ W2a,
    const float* __restrict__ W1m, const float* __restrict__ W2m,
    const float* __restrict__ ge, const float* __restrict__ ve,
    __hip_bfloat16* __restrict__ dstp) {
  __bf16* dst = (__bf16*)dstp;
  const int mat = blockIdx.y;
  const float* src;
  __bf16* d;
  int nsh;
  if (mat == 0)      { src = W1a + 65536; d = dst;         nsh = 8; }
  else if (mat == 1) { src = W2a;         d = dst + 32768; nsh = 7; }
  else if (mat == 2) { src = W1m + 65536; d = dst + 65536; nsh = 8; }
  else               { src = W2m;         d = dst + 98304; nsh = 7; }
  const int nmask = (1 << nsh) - 1;
  const int base = (blockIdx.x * 256 + threadIdx.x) * 4;
#pragma unroll
  for (int i = 0; i < 4; ++i) {
    int s = base + i;
    int k = s >> nsh, n = s & nmask;
    float v = src[s];
    if (mat == 2) v *= sqrtf(ve[k] + 1e-3f) / ge[k];  // 1/sc_e[k]
    int g = k >> 3;
    if (nsh == 8) {
      int gs = (g & 8) | ((g ^ n) & 7);
      d[n * 128 + gs * 8 + (k & 7)] = (__bf16)v;
    } else {
      int gs = (g ^ n) & 7;
      d[((k >> 6) << 13) + (n << 6) + (gs << 3) + (k & 7)] = (__bf16)v;
    }
  }
}

// ---------------- kernel A: edge MLP -> BN'd fp32 edges (final) --------------
__global__ void __launch_bounds__(512, 2) edge_mlp_kernel(
    const float* __restrict__ edges, const float* __restrict__ mask,
    const float* __restrict__ b2a, const float* __restrict__ ge,
    const float* __restrict__ be, const float* __restrict__ me,
    const float* __restrict__ ve, const float* __restrict__ PaT,
    const float* __restrict__ Qab, const __hip_bfloat16* __restrict__ Wsw,
    float* __restrict__ edges_out) {
  __shared__ __align__(16) char sW[131072];   // W1ae^sw 64KB | W2a^sw 64KB
  __shared__ __align__(16) char sH1[16384];   // per-wave-private 2KB stripes

  const int t = threadIdx.x;
  const int lane = t & 63, wv = t >> 6;
  const int cl = lane & 15, qd = lane >> 4;
  const int m0 = wv << 4;  // 16-row stripe per wave

  {  // stage both weight matrices ONCE (pre-swizzled in global; linear copy)
    const char* g = (const char*)Wsw;
    for (int o = wv * 1024; o < 131072; o += 8192)
      GLDS(g + o + lane * 16, sW + o);
  }
  // per-lane epilogue constants (cols nt*16+cl)
  float b2v[8], scv[8], shv[8];
#pragma unroll
  for (int nt = 0; nt < 8; ++nt) {
    const int col = nt * 16 + cl;
    b2v[nt] = b2a[col];
    float sc = ge[col] * rsqrtf(ve[col] + 1e-3f);
    scv[nt] = sc;
    shv[nt] = be[col] - me[col] * sc;
  }
  __syncthreads();  // weights resident; last barrier in this kernel

  const int tile0 = blockIdx.x * 8;
  const int bb = tile0 >> 7;  // constant per block (8 | 128)

  bf16x8 xfA[4];
  {
    const float* Xb = edges + ((size_t)tile0 << 14);
#pragma unroll
    for (int ks = 0; ks < 4; ++ks)
      xfA[ks] = load8_cvt(Xb + (m0 + cl) * 128 + ks * 32 + qd * 8);
  }

#pragma unroll 1
  for (int ti = 0; ti < 8; ++ti) {
    const int p = (tile0 + ti) & 127;
    bf16x8 xfN[4];  // prefetch next tile's X (wraps to tile0 on last: unused)
    {
      const float* Xb = edges + ((size_t)(tile0 + ((ti + 1) & 7)) << 14);
#pragma unroll
      for (int ks = 0; ks < 4; ++ks)
        xfN[ks] = load8_cvt(Xb + (m0 + cl) * 128 + ks * 32 + qd * 8);
    }
    const float4 mv =
        *(const float4*)&mask[(bb << 14) + (p << 7) + m0 + qd * 4];
    const float* Qr = Qab + ((size_t)((bb << 7) + p) << 8);

    f32x4 ne[8];
#pragma unroll
    for (int nt = 0; nt < 8; ++nt)
      ne[nt] = (f32x4){b2v[nt], b2v[nt], b2v[nt], b2v[nt]};

#pragma unroll
    for (int h = 0; h < 4; ++h) {
      f32x4 a1[4];
#pragma unroll
      for (int nt = 0; nt < 4; ++nt) {
        const int col = h * 64 + nt * 16 + cl;
        const float qv = Qr[col];
        const float4 pa =
            *(const float4*)&PaT[((size_t)((bb << 8) + col) << 7) + m0 + qd * 4];
        a1[nt] = (f32x4){pa.x + qv, pa.y + qv, pa.z + qv, pa.w + qv};
      }
#pragma unroll
      for (int ks = 0; ks < 4; ++ks)
#pragma unroll
        for (int nt = 0; nt < 4; ++nt) {
          const int nl = nt * 16 + cl;
          const int g = ks * 4 + qd;
          const int gs = (g & 8) | ((g ^ nl) & 7);
          bf16x8 bw = *(const bf16x8*)(sW + (h * 64 + nl) * 256 + gs * 16);
          a1[nt] = __builtin_amdgcn_mfma_f32_16x16x32_bf16(xfA[ks], bw, a1[nt], 0, 0, 0);
        }
      // H1 roundtrip through this wave's private LDS stripe (no barrier:
      // same-wave DS ops are ordered; regions disjoint across waves)
#pragma unroll
      for (int nt = 0; nt < 4; ++nt) {
        const int kq = nt * 16 + cl;
#pragma unroll
        for (int r = 0; r < 4; ++r) {
          const int m = m0 + qd * 4 + r;
          float v = a1[nt][r];
          v = v > 0.f ? v : 0.f;
          *(__bf16*)(sH1 + m * 128 + ((((kq >> 3) ^ m) & 7) << 4) +
                     ((kq & 7) << 1)) = (__bf16)v;
        }
      }
      bf16x8 hf[2];
#pragma unroll
      for (int ks = 0; ks < 2; ++ks) {
        const int m = m0 + cl;
        const int gs = ((ks * 4 + qd) ^ m) & 7;
        hf[ks] = *(const bf16x8*)(sH1 + m * 128 + gs * 16);
      }
#pragma unroll
      for (int ks = 0; ks < 2; ++ks)
#pragma unroll
        for (int nt = 0; nt < 8; ++nt) {
          const int n = nt * 16 + cl;
          const int gs = ((ks * 4 + qd) ^ n) & 7;
          bf16x8 bw =
              *(const bf16x8*)(sW + 65536 + h * 16384 + n * 128 + gs * 16);
          ne[nt] = __builtin_amdgcn_mfma_f32_16x16x32_bf16(hf[ks], bw, ne[nt], 0, 0, 0);
        }
    }
    // epilogue: relu*mask -> edge BN -> final fp32 edges
    float* Ob = edges_out + ((size_t)(tile0 + ti) << 14);
#pragma unroll
    for (int nt = 0; nt < 8; ++nt) {
      const int col = nt * 16 + cl;
#pragma unroll
      for (int r = 0; r < 4; ++r) {
        const int m = m0 + qd * 4 + r;
        float v = ne[nt][r];
        v = v > 0.f ? v : 0.f;
        const float mr = (r == 0 ? mv.x : r == 1 ? mv.y : r == 2 ? mv.z : mv.w);
        Ob[m * 128 + col] = (v * mr) * scv[nt] + shv[nt];
      }
    }
#pragma unroll
    for (int i = 0; i < 4; ++i) xfA[i] = xfN[i];
  }
}

// ---------- kernel B: message MLP (un-BN folded) + aggregate ----------
__global__ void __launch_bounds__(512, 2) msg_mlp_kernel(
    const float* __restrict__ Yedges, const float* __restrict__ mask,
    const float* __restrict__ b2m, const float* __restrict__ PmT,
    const float* __restrict__ Qmb, const __hip_bfloat16* __restrict__ Wsw,
    float* __restrict__ agg) {
  __shared__ __align__(16) char sW[131072];   // W1me^sw 64KB | W2m^sw 64KB
  __shared__ __align__(16) char sH1[16384];

  const int t = threadIdx.x;
  const int lane = t & 63, wv = t >> 6;
  const int cl = lane & 15, qd = lane >> 4;
  const int m0 = wv << 4;

  {
    const char* g = (const char*)Wsw;
    for (int o = wv * 1024; o < 131072; o += 8192)
      GLDS(g + o + lane * 16, sW + o);
  }
  float b2v[8];
#pragma unroll
  for (int nt = 0; nt < 8; ++nt) b2v[nt] = b2m[nt * 16 + cl];
  __syncthreads();

  const int tile0 = blockIdx.x * 8;
  const int bb = tile0 >> 7;

  bf16x8 xfA[4];
  {
    const float* Xb = Yedges + ((size_t)tile0 << 14);
#pragma unroll
    for (int ks = 0; ks < 4; ++ks)
      xfA[ks] = load8_cvt(Xb + (m0 + cl) * 128 + ks * 32 + qd * 8);
  }

#pragma unroll 1
  for (int ti = 0; ti < 8; ++ti) {
    const int p = (tile0 + ti) & 127;
    bf16x8 xfN[4];
    {
      const float* Xb = Yedges + ((size_t)(tile0 + ((ti + 1) & 7)) << 14);
#pragma unroll
      for (int ks = 0; ks < 4; ++ks)
        xfN[ks] = load8_cvt(Xb + (m0 + cl) * 128 + ks * 32 + qd * 8);
    }
    const float4 mv =
        *(const float4*)&mask[(bb << 14) + (p << 7) + m0 + qd * 4];
    const float* Qr = Qmb + ((size_t)((bb << 7) + p) << 8);

    f32x4 ms[8];
#pragma unroll
    for (int nt = 0; nt < 8; ++nt)
      ms[nt] = (f32x4){b2v[nt], b2v[nt], b2v[nt], b2v[nt]};

#pragma unroll
    for (int h = 0; h < 4; ++h) {
      f32x4 a1[4];
#pragma unroll
      for (int nt = 0; nt < 4; ++nt) {
        const int col = h * 64 + nt * 16 + cl;
        const float qv = Qr[col];
        const float4 pa =
            *(const float4*)&PmT[((size_t)((bb << 8) + col) << 7) + m0 + qd * 4];
        a1[nt] = (f32x4){pa.x + qv, pa.y + qv, pa.z + qv, pa.w + qv};
      }
#pragma unroll
      for (int ks = 0; ks < 4; ++ks)
#pragma unroll
        for (int nt = 0; nt < 4; ++nt) {
          const int nl = nt * 16 + cl;
          const int g = ks * 4 + qd;
          const int gs = (g & 8) | ((g ^ nl) & 7);
          bf16x8 bw = *(const bf16x8*)(sW + (h * 64 + nl) * 256 + gs * 16);
          a1[nt] = __builtin_amdgcn_mfma_f32_16x16x32_bf16(xfA[ks], bw, a1[nt], 0, 0, 0);
        }
#pragma unroll
      for (int nt = 0; nt < 4; ++nt) {
        const int kq = nt * 16 + cl;
#pragma unroll
        for (int r = 0; r < 4; ++r) {
          const int m = m0 + qd * 4 + r;
          float v = a1[nt][r];
          v = v > 0.f ? v : 0.f;
          *(__bf16*)(sH1 + m * 128 + ((((kq >> 3) ^ m) & 7) << 4) +
                     ((kq & 7) << 1)) = (__bf16)v;
        }
      }
      bf16x8 hf[2];
#pragma unroll
      for (int ks = 0; ks < 2; ++ks) {
        const int m = m0 + cl;
        const int gs = ((ks * 4 + qd) ^ m) & 7;
        hf[ks] = *(const bf16x8*)(sH1 + m * 128 + gs * 16);
      }
#pragma unroll
      for (int ks = 0; ks < 2; ++ks)
#pragma unroll
        for (int nt = 0; nt < 8; ++nt) {
          const int n = nt * 16 + cl;
          const int gs = ((ks * 4 + qd) ^ n) & 7;
          bf16x8 bw =
              *(const bf16x8*)(sW + 65536 + h * 16384 + n * 128 + gs * 16);
          ms[nt] = __builtin_amdgcn_mfma_f32_16x16x32_bf16(hf[ks], bw, ms[nt], 0, 0, 0);
        }
    }
    // epilogue: relu*mask, column-sum over wave's 16 rows, atomicAdd (agg
    // pre-zeroed by proj; 8 wave-contributions per element, fp32 atomics)
#pragma unroll
    for (int nt = 0; nt < 8; ++nt) {
      float s = 0.f;
#pragma unroll
      for (int r = 0; r < 4; ++r) {
        float v = ms[nt][r];
        v = v > 0.f ? v : 0.f;
        const float mr = (r == 0 ? mv.x : r == 1 ? mv.y : r == 2 ? mv.z : mv.w);
        s += v * mr;
      }
      s += __shfl_xor(s, 16);
      s += __shfl_xor(s, 32);
      if (lane < 16)
        atomicAdd(&agg[((size_t)((bb << 7) + p) << 7) + nt * 16 + lane], s);
    }
#pragma unroll
    for (int i = 0; i < 4; ++i) xfA[i] = xfN[i];
  }
}

// ---------------- kernel C: update MLP + node BN (VALU, tiny) ----------------
__global__ void __launch_bounds__(256) update_kernel(
    const float* __restrict__ nodes, const float* __restrict__ agg,
    const float* __restrict__ W1u, const float* __restrict__ b1u,
    const float* __restrict__ W2u, const float* __restrict__ b2u,
    const float* __restrict__ gn, const float* __restrict__ btn,
    const float* __restrict__ mn, const float* __restrict__ vn,
    float* __restrict__ out) {
  __shared__ float x[8][256];
  __shared__ float hh[8][256];
  const int t = threadIdx.x;
  const int r0 = blockIdx.x * 8;
  for (int i = t; i < 2048; i += 256) {
    int r = i >> 8, c = i & 255;
    x[r][c] = (c < 128) ? nodes[(r0 + r) * 128 + c] : agg[(r0 + r) * 128 + (c - 128)];
  }
  __syncthreads();
  float acc[8];
  {
    float bv = b1u[t];
#pragma unroll
    for (int r = 0; r < 8; ++r) acc[r] = bv;
  }
  for (int k = 0; k < 256; ++k) {
    float w = W1u[k * 256 + t];
#pragma unroll
    for (int r = 0; r < 8; ++r) acc[r] += x[r][k] * w;
  }
#pragma unroll
  for (int r = 0; r < 8; ++r) hh[r][t] = acc[r] > 0.f ? acc[r] : 0.f;
  __syncthreads();
  const int j = t & 127, half = t >> 7;
  float a2[4];
  {
    float bv = b2u[j];
#pragma unroll
    for (int r = 0; r < 4; ++r) a2[r] = bv;
  }
  for (int k = 0; k < 256; ++k) {
    float w = W2u[k * 128 + j];
#pragma unroll
    for (int r = 0; r < 4; ++r) a2[r] += hh[half * 4 + r][k] * w;
  }
  float sc = gn[j] * rsqrtf(vn[j] + 1e-3f);
  float sh = btn[j] - mn[j] * sc;
#pragma unroll
  for (int r = 0; r < 4; ++r) {
    float v = a2[r] > 0.f ? a2[r] : 0.f;
    out[(r0 + half * 4 + r) * 128 + j] = v * sc + sh;
  }
}

extern "C" void kernel_launch(void* const* d_in, const int* in_sizes, int n_in,
                              void* d_out, int out_size, void* d_ws,
                              size_t ws_size, hipStream_t stream) {
  (void)in_sizes; (void)n_in; (void)out_size; (void)ws_size;
  const float* nodes = (const float*)d_in[0];
  const float* edges = (const float*)d_in[1];
  const float* mask = (const float*)d_in[2];
  const float* W1a = (const float*)d_in[3];
  const float* b1a = (const float*)d_in[4];
  const float* W2a = (const float*)d_in[5];
  const float* b2a = (const float*)d_in[6];
  const float* W1m = (const float*)d_in[7];
  const float* b1m = (const float*)d_in[8];
  const float* W2m = (const float*)d_in[9];
  const float* b2m = (const float*)d_in[10];
  const float* W1u = (const float*)d_in[11];
  const float* b1u = (const float*)d_in[12];
  const float* W2u = (const float*)d_in[13];
  const float* b2u = (const float*)d_in[14];
  const float* gn = (const float*)d_in[15];
  const float* btn = (const float*)d_in[16];
  const float* mn = (const float*)d_in[17];
  const float* vn = (const float*)d_in[18];
  const float* ge = (const float*)d_in[19];
  const float* be = (const float*)d_in[20];
  const float* me = (const float*)d_in[21];
  const float* ve = (const float*)d_in[22];

  float* out_nodes = (float*)d_out;
  float* out_edges = (float*)d_out + 262144;

  char* ws = (char*)d_ws;
  float* PaT = (float*)(ws);
  float* Qab = (float*)(ws + ((size_t)1 << 21));
  float* PmT = (float*)(ws + ((size_t)2 << 21));
  float* Qmb = (float*)(ws + ((size_t)3 << 21));
  float* agg = (float*)(ws + ((size_t)4 << 21));
  __hip_bfloat16* Wsw = (__hip_bfloat16*)(ws + ((size_t)4 << 21) + ((size_t)1 << 20));

  proj_kernel<<<dim3(256, 4), 256, 0, stream>>>(nodes, W1a, b1a, W1m, b1m, ge,
                                                be, me, ve, PaT, agg);
  wswz_kernel<<<dim3(32, 4), 256, 0, stream>>>(W1a, W2a, W1m, W2m, ge, ve, Wsw);
  edge_mlp_kernel<<<256, 512, 0, stream>>>(edges, mask, b2a, ge, be, me, ve,
                                           PaT, Qab, Wsw, out_edges);
  msg_mlp_kernel<<<256, 512, 0, stream>>>(out_edges, mask, b2m, PmT, Qmb,
                                          Wsw + 65536, agg);
  update_kernel<<<256, 256, 0, stream>>>(nodes, agg, W1u, b1u, W2u, b2u, gn, btn,
                                         mn, vn, out_nodes);
}